// Round 5
// baseline (2484.250 us; speedup 1.0000x reference)
//
#include <hip/hip_runtime.h>
#include <math.h>

#define BB 4
#define TT 2048
#define DD 1024
#define HH 128
#define EPSF 1e-6f
#define BT (BB*TT)   // 8192
#define NI (TT/2)    // 1024 double-steps

typedef float f32x2 __attribute__((ext_vector_type(2)));

// ---------------------------------------------------------------------------
// Projection: P[bt][h] = sum_d x[bt][d] * W[h][d] + bias[h]
// ---------------------------------------------------------------------------
__global__ __launch_bounds__(256) void proj_kernel(
    const float* __restrict__ x,
    const float* __restrict__ Wq, const float* __restrict__ bq,
    const float* __restrict__ Wk, const float* __restrict__ bk,
    const float* __restrict__ Wv, const float* __restrict__ bv,
    float* __restrict__ Q, float* __restrict__ K, float* __restrict__ V)
{
    const int which = blockIdx.y;
    const float* W    = (which == 0) ? Wq : (which == 1) ? Wk : Wv;
    const float* bias = (which == 0) ? bq : (which == 1) ? bk : bv;
    float* P          = (which == 0) ? Q  : (which == 1) ? K  : V;

    const int row0 = blockIdx.x * 64;

    __shared__ float xT[32][68];
    __shared__ float wT[32][132];

    const int tid = threadIdx.x;
    const int tx = tid & 15;
    const int ty = tid >> 4;

    float acc[4][8];
    #pragma unroll
    for (int i = 0; i < 4; i++)
        #pragma unroll
        for (int j = 0; j < 8; j++) acc[i][j] = 0.f;

    for (int k0 = 0; k0 < DD; k0 += 32) {
        #pragma unroll
        for (int l = 0; l < 2; l++) {
            int f = tid + l * 256;
            int r = f >> 3;
            int cg = f & 7;
            float4 v = *(const float4*)(x + (size_t)(row0 + r) * DD + k0 + cg * 4);
            xT[cg*4+0][r] = v.x; xT[cg*4+1][r] = v.y;
            xT[cg*4+2][r] = v.z; xT[cg*4+3][r] = v.w;
        }
        #pragma unroll
        for (int l = 0; l < 4; l++) {
            int f = tid + l * 256;
            int h = f >> 3;
            int cg = f & 7;
            float4 v = *(const float4*)(W + (size_t)h * DD + k0 + cg * 4);
            wT[cg*4+0][h] = v.x; wT[cg*4+1][h] = v.y;
            wT[cg*4+2][h] = v.z; wT[cg*4+3][h] = v.w;
        }
        __syncthreads();
        #pragma unroll
        for (int kk = 0; kk < 32; kk++) {
            float4 xv = *(const float4*)&xT[kk][ty * 4];
            float4 w0 = *(const float4*)&wT[kk][tx * 8];
            float4 w1 = *(const float4*)&wT[kk][tx * 8 + 4];
            float xa[4] = {xv.x, xv.y, xv.z, xv.w};
            float wa[8] = {w0.x, w0.y, w0.z, w0.w, w1.x, w1.y, w1.z, w1.w};
            #pragma unroll
            for (int i = 0; i < 4; i++)
                #pragma unroll
                for (int j = 0; j < 8; j++)
                    acc[i][j] += xa[i] * wa[j];
        }
        __syncthreads();
    }

    #pragma unroll
    for (int i = 0; i < 4; i++) {
        int row = row0 + ty * 4 + i;
        #pragma unroll
        for (int j = 0; j < 8; j++) acc[i][j] += bias[tx * 8 + j];
        float4 o0 = {acc[i][0], acc[i][1], acc[i][2], acc[i][3]};
        float4 o1 = {acc[i][4], acc[i][5], acc[i][6], acc[i][7]};
        *(float4*)(P + (size_t)row * HH + tx * 8)     = o0;
        *(float4*)(P + (size_t)row * HH + tx * 8 + 4) = o1;
    }
}

// ---------------------------------------------------------------------------
// Precompute per-step scalars: rns[row] = (1/(||k||+eps), k.q).
// ---------------------------------------------------------------------------
__global__ __launch_bounds__(256) void rns_kernel(
    const float* __restrict__ K, const float* __restrict__ Q,
    float2* __restrict__ rns)
{
    const int row  = blockIdx.x * 4 + (threadIdx.x >> 6);
    const int lane = threadIdx.x & 63;
    const float* kp = K + (size_t)row * HH;
    const float* qp = Q + (size_t)row * HH;
    float k0 = kp[lane], k1 = kp[lane + 64];
    float q0 = qp[lane], q1 = qp[lane + 64];
    float p2  = k0 * k0 + k1 * k1;
    float pkq = k0 * q0 + k1 * q1;
    #pragma unroll
    for (int off = 32; off; off >>= 1) {
        p2  += __shfl_xor(p2, off);
        pkq += __shfl_xor(pkq, off);
    }
    if (lane == 0) {
        float rn = 1.0f / (sqrtf(p2) + EPSF);
        rns[row] = make_float2(rn, pkq);
    }
}

// quad butterfly sum via DPP (VALU only, no DS pipe)
__device__ __forceinline__ float quad_red(float x) {
    x += __int_as_float(__builtin_amdgcn_mov_dpp(__float_as_int(x), 0xB1, 0xF, 0xF, true)); // [1,0,3,2]
    x += __int_as_float(__builtin_amdgcn_mov_dpp(__float_as_int(x), 0x4E, 0xF, 0xF, true)); // [2,3,0,1]
    return x;
}

// ---------------------------------------------------------------------------
// Sequential scan v6: TWO timesteps per barrier (rank-2 Sherman-Morrison).
// 512 threads; thread owns A[r][c0..c0+31], M[r][c0..c0+31] (f32x2[16] each);
// r = tid>>2, q4 = tid&3, c0 = q4*32.
//
// Per double-step (t=2i, t+1), with A = A_t, M = M_t in registers:
//   pre-barrier : y1 = A k1, y2 = A k2 (quad-reduced, broadcast to LDS);
//                 x1 = M q1, x2 = M q2 (kept in quad registers)
//   post-barrier: read y1,y2 at my cols; 6 dots e11=k1.y1, e21=k2.y1,
//                 e22=k2.y2, g11=q1.y1, g21=q2.y1, g22=q2.y2;
//                 d1 = 1+rn1^2 e11, beta = rn1^2 e21 / d1,
//                 p2 = y2 - beta y1 (= A_{t+1} k2), d2 = 1+rn2^2(e22-beta e21)
//                 A -= (rn1^2 y1r/d1) y1 + (rn2^2 p2r/d2) p2
//                 M += (v1r s1 rn1/d1) y1 + (v2r s2 rn2/d2) p2
//                 o1 = x1 + cM1 g11 ; o2 = x2 + cM1 g21 + cM2 (g22 - beta g21)
// Exact algebra (no approximation beyond v_rcp). Halves barriers, LDS
// round-trips and scalar-chain events per step for ~25% more VALU.
//
// k/q/v staging is TRIPLE-buffered: the post-barrier dot phase re-reads the
// current slot, which would race with next-iter staging under double-buffer.
// Y broadcast stays double-buffered (same ordering argument as v4).
// Padded layout (stride 36 per group of 32) is v4's proven conflict-free one.
// ---------------------------------------------------------------------------
__global__ __launch_bounds__(512, 1) void scan_kernel(
    const float* __restrict__ Q, const float* __restrict__ K,
    const float* __restrict__ V, const float2* __restrict__ rns,
    float* __restrict__ O)
{
    const int b   = blockIdx.x;
    const int tid = threadIdx.x;
    const int r   = tid >> 2;     // row 0..127
    const int q4  = tid & 3;      // column quarter
    const int c0  = q4 * 32;

    __shared__ float Ybc[2][2][4 * 36];     // [buf][y1/y2], padded
    __shared__ float kqs[3][4][4 * 36];     // [slot][k1,k2,q1,q2], padded
    __shared__ float vbuf[3][2][128];       // [slot][v1,v2], linear

    f32x2 A2[16], M2[16];
    #pragma unroll
    for (int j = 0; j < 16; j++) {
        M2[j] = (f32x2){0.f, 0.f};
        A2[j].x = (c0 + 2 * j     == r) ? 1.0f : 0.0f;
        A2[j].y = (c0 + 2 * j + 1 == r) ? 1.0f : 0.0f;
    }

    const float* Qb = Q + (size_t)b * TT * HH;
    const float* Kb = K + (size_t)b * TT * HH;
    const float* Vb = V + (size_t)b * TT * HH;
    float*       Ob = O + (size_t)b * TT * HH;
    const float2* rns_b = rns + (size_t)b * TT;

    const int woff = (r >> 5) * 36 + (r & 31);   // my row's slot (write)
    const int roff = q4 * 36;                    // my read base (padded)

    // loader role: 192 threads, one float4 each per double-step.
    // which: 0=k(even) 1=k(odd) 2=q(even) 3=q(odd) 4=v(even) 5=v(odd)
    const bool ldr   = tid < 192;
    const int  which = tid >> 5;
    const int  l32   = tid & 31;
    const int  par   = which & 1;
    const float* src = (which < 2) ? Kb : (which < 4) ? Qb : Vb;
    const int  lpoff = (l32 >> 3) * 36 + (l32 & 7) * 4;  // padded f4 offset

    float4 pld = {0.f, 0.f, 0.f, 0.f};

    // prologue: stage iter 0 into slot 0; prefetch iter 1
    if (ldr) {
        float4 d0 = *(const float4*)(src + (size_t)par * HH + l32 * 4);
        if (which < 4) *(float4*)&kqs[0][which][lpoff]    = d0;
        else           *(float4*)&vbuf[0][which - 4][l32 * 4] = d0;
        pld = *(const float4*)(src + (size_t)(2 + par) * HH + l32 * 4);
    }
    float4 rs_cur = ((const float4*)rns_b)[0];
    float4 rs_nxt = ((const float4*)rns_b)[1];
    __syncthreads();   // slot 0 ready

    int s = 0;
    for (int i = 0; i < NI; ++i) {
        const int sn = (s == 2) ? 0 : s + 1;
        const int yb = i & 1;

        const float* k1p = &kqs[s][0][roff];
        const float* k2p = &kqs[s][1][roff];
        const float* q1p = &kqs[s][2][roff];
        const float* q2p = &kqs[s][3][roff];

        // --- y1 = A k1, y2 = A k2 partials over my 32 cols (packed)
        f32x2 y1v = {0.f, 0.f}, y2v = {0.f, 0.f};
        #pragma unroll
        for (int j = 0; j < 8; ++j) {
            float4 tk1 = *(const float4*)(k1p + 4 * j);
            float4 tk2 = *(const float4*)(k2p + 4 * j);
            y1v += A2[2*j] * (f32x2){tk1.x, tk1.y} + A2[2*j+1] * (f32x2){tk1.z, tk1.w};
            y2v += A2[2*j] * (f32x2){tk2.x, tk2.y} + A2[2*j+1] * (f32x2){tk2.z, tk2.w};
        }
        float y1r = quad_red(y1v.x + y1v.y);
        float y2r = quad_red(y2v.x + y2v.y);
        if (q4 == 0) {
            Ybc[yb][0][woff] = y1r;
            Ybc[yb][1][woff] = y2r;
        }

        // --- x1 = M q1, x2 = M q2 (fills pre-barrier gap)
        f32x2 x1v = {0.f, 0.f}, x2v = {0.f, 0.f};
        #pragma unroll
        for (int j = 0; j < 8; ++j) {
            float4 tq1 = *(const float4*)(q1p + 4 * j);
            float4 tq2 = *(const float4*)(q2p + 4 * j);
            x1v += M2[2*j] * (f32x2){tq1.x, tq1.y} + M2[2*j+1] * (f32x2){tq1.z, tq1.w};
            x2v += M2[2*j] * (f32x2){tq2.x, tq2.y} + M2[2*j+1] * (f32x2){tq2.z, tq2.w};
        }
        float x1 = quad_red(x1v.x + x1v.y);
        float x2 = quad_red(x2v.x + x2v.y);
        float v1r = vbuf[s][0][r];
        float v2r = vbuf[s][1][r];

        // --- stage iter i+1 into slot sn; prefetch iter i+2
        if (ldr && i + 1 < NI) {
            if (which < 4) *(float4*)&kqs[sn][which][lpoff]    = pld;
            else           *(float4*)&vbuf[sn][which - 4][l32 * 4] = pld;
            if (i + 2 < NI)
                pld = *(const float4*)(src + (size_t)(2 * (i + 2) + par) * HH + l32 * 4);
        }

        __syncthreads();   // the ONE barrier: Ybc[yb] + slot sn ready

        // --- read y1,y2 at my cols; 6 dot partials (streamed from LDS)
        f32x2 a1[16], a2[16];
        f32x2 e11v = {0,0}, e21v = {0,0}, e22v = {0,0};
        f32x2 g11v = {0,0}, g21v = {0,0}, g22v = {0,0};
        #pragma unroll
        for (int j = 0; j < 8; ++j) {
            float4 t1  = *(const float4*)&Ybc[yb][0][roff + 4 * j];
            float4 t2  = *(const float4*)&Ybc[yb][1][roff + 4 * j];
            float4 tk1 = *(const float4*)(k1p + 4 * j);
            float4 tk2 = *(const float4*)(k2p + 4 * j);
            float4 tq1 = *(const float4*)(q1p + 4 * j);
            float4 tq2 = *(const float4*)(q2p + 4 * j);
            f32x2 a1lo = {t1.x, t1.y}, a1hi = {t1.z, t1.w};
            f32x2 a2lo = {t2.x, t2.y}, a2hi = {t2.z, t2.w};
            a1[2*j] = a1lo; a1[2*j+1] = a1hi;
            a2[2*j] = a2lo; a2[2*j+1] = a2hi;
            e11v += a1lo * (f32x2){tk1.x, tk1.y} + a1hi * (f32x2){tk1.z, tk1.w};
            e21v += a1lo * (f32x2){tk2.x, tk2.y} + a1hi * (f32x2){tk2.z, tk2.w};
            g11v += a1lo * (f32x2){tq1.x, tq1.y} + a1hi * (f32x2){tq1.z, tq1.w};
            g21v += a1lo * (f32x2){tq2.x, tq2.y} + a1hi * (f32x2){tq2.z, tq2.w};
            e22v += a2lo * (f32x2){tk2.x, tk2.y} + a2hi * (f32x2){tk2.z, tk2.w};
            g22v += a2lo * (f32x2){tq2.x, tq2.y} + a2hi * (f32x2){tq2.z, tq2.w};
        }
        float e11 = quad_red(e11v.x + e11v.y);
        float e21 = quad_red(e21v.x + e21v.y);
        float e22 = quad_red(e22v.x + e22v.y);
        float g11 = quad_red(g11v.x + g11v.y);
        float g21 = quad_red(g21v.x + g21v.y);
        float g22 = quad_red(g22v.x + g22v.y);

        // --- scalars (exact rank-2 recurrence)
        const float rn1 = rs_cur.x, s1 = rs_cur.y;
        const float rn2 = rs_cur.z, s2 = rs_cur.w;
        const float rn1sq = rn1 * rn1;
        const float rn2sq = rn2 * rn2;
        const float i1   = __builtin_amdgcn_rcpf(1.0f + rn1sq * e11);
        const float beta = rn1sq * e21 * i1;
        const float i2   = __builtin_amdgcn_rcpf(1.0f + rn2sq * (e22 - beta * e21));
        const float p2r  = y2r - beta * y1r;
        const float cA1  = rn1sq * y1r * i1;
        const float cA2  = rn2sq * p2r * i2;
        const float cM1  = v1r * s1 * rn1 * i1;
        const float cM2  = v2r * s2 * rn2 * i2;
        const float o1   = x1 + cM1 * g11;
        const float o2   = x2 + cM1 * g21 + cM2 * (g22 - beta * g21);
        if (q4 == 0) {
            Ob[(size_t)(2 * i)     * HH + r] = o1;
            Ob[(size_t)(2 * i + 1) * HH + r] = o2;
        }

        // --- fused rank-2 updates
        const f32x2 bv   = {beta, beta};
        const f32x2 cA1v = {cA1, cA1}, cA2v = {cA2, cA2};
        const f32x2 cM1v = {cM1, cM1}, cM2v = {cM2, cM2};
        #pragma unroll
        for (int j = 0; j < 16; ++j) {
            f32x2 p2 = a2[j] - bv * a1[j];
            A2[j] = A2[j] - cA1v * a1[j] - cA2v * p2;
            M2[j] = M2[j] + cM1v * a1[j] + cM2v * p2;
        }

        rs_cur = rs_nxt;
        if (i + 2 < NI) rs_nxt = ((const float4*)rns_b)[i + 2];
        s = sn;
        // Slot lifetime: slot sn written pre-barrier-i, read through iter
        // i+1's post-phase, next overwritten at iter i+3 pre-phase (after
        // barrier i+2) -> safe. Ybc[yb] read post-barrier-i, overwritten at
        // iter i+2 pre-phase (after barrier i+1) -> safe.
    }
}

// ---------------------------------------------------------------------------
// Output: out[bt][d] = sum_h O[bt][h] * Wo[d][h] + bo[d]
// ---------------------------------------------------------------------------
__global__ __launch_bounds__(256) void out_kernel(
    const float* __restrict__ O, const float* __restrict__ Wo,
    const float* __restrict__ bo, float* __restrict__ out)
{
    const int row0 = blockIdx.x * 64;
    const int d0   = blockIdx.y * 128;

    __shared__ float oT[32][68];
    __shared__ float woT[32][132];

    const int tid = threadIdx.x;
    const int tx = tid & 15;
    const int ty = tid >> 4;

    float acc[4][8];
    #pragma unroll
    for (int i = 0; i < 4; i++)
        #pragma unroll
        for (int j = 0; j < 8; j++) acc[i][j] = 0.f;

    for (int k0 = 0; k0 < HH; k0 += 32) {
        #pragma unroll
        for (int l = 0; l < 2; l++) {
            int f = tid + l * 256;
            int r = f >> 3;
            int cg = f & 7;
            float4 v = *(const float4*)(O + (size_t)(row0 + r) * HH + k0 + cg * 4);
            oT[cg*4+0][r] = v.x; oT[cg*4+1][r] = v.y;
            oT[cg*4+2][r] = v.z; oT[cg*4+3][r] = v.w;
        }
        #pragma unroll
        for (int l = 0; l < 4; l++) {
            int f = tid + l * 256;
            int d = f >> 3;
            int cg = f & 7;
            float4 v = *(const float4*)(Wo + (size_t)(d0 + d) * HH + k0 + cg * 4);
            woT[cg*4+0][d] = v.x; woT[cg*4+1][d] = v.y;
            woT[cg*4+2][d] = v.z; woT[cg*4+3][d] = v.w;
        }
        __syncthreads();
        #pragma unroll
        for (int kk = 0; kk < 32; kk++) {
            float4 ov = *(const float4*)&oT[kk][ty * 4];
            float4 w0 = *(const float4*)&woT[kk][tx * 8];
            float4 w1 = *(const float4*)&woT[kk][tx * 8 + 4];
            float oa[4] = {ov.x, ov.y, ov.z, ov.w};
            float wa[8] = {w0.x, w0.y, w0.z, w0.w, w1.x, w1.y, w1.z, w1.w};
            #pragma unroll
            for (int i = 0; i < 4; i++)
                #pragma unroll
                for (int j = 0; j < 8; j++)
                    acc[i][j] += oa[i] * wa[j];
        }
        __syncthreads();
    }

    #pragma unroll
    for (int i = 0; i < 4; i++) {
        int row = row0 + ty * 4 + i;
        #pragma unroll
        for (int j = 0; j < 8; j++) acc[i][j] += bo[d0 + tx * 8 + j];
        float4 o0 = {acc[i][0], acc[i][1], acc[i][2], acc[i][3]};
        float4 o1 = {acc[i][4], acc[i][5], acc[i][6], acc[i][7]};
        *(float4*)(out + (size_t)row * DD + d0 + tx * 8)     = o0;
        *(float4*)(out + (size_t)row * DD + d0 + tx * 8 + 4) = o1;
    }
}

extern "C" void kernel_launch(void* const* d_in, const int* in_sizes, int n_in,
                              void* d_out, int out_size, void* d_ws, size_t ws_size,
                              hipStream_t stream) {
    const float* x  = (const float*)d_in[0];
    const float* Wq = (const float*)d_in[1];
    const float* bq = (const float*)d_in[2];
    const float* Wk = (const float*)d_in[3];
    const float* bk = (const float*)d_in[4];
    const float* Wv = (const float*)d_in[5];
    const float* bv = (const float*)d_in[6];
    const float* Wo = (const float*)d_in[7];
    const float* bo = (const float*)d_in[8];
    float* out = (float*)d_out;

    float* ws = (float*)d_ws;
    float* Q = ws;
    float* K = ws + (size_t)BT * HH;
    float* V = ws + (size_t)2 * BT * HH;
    float* O = ws + (size_t)3 * BT * HH;
    // rns scalars live in d_out: it is scratch until out_kernel runs
    float2* rns = (float2*)d_out;

    dim3 pgrid(BT / 64, 3);
    proj_kernel<<<pgrid, 256, 0, stream>>>(x, Wq, bq, Wk, bk, Wv, bv, Q, K, V);

    rns_kernel<<<BT / 4, 256, 0, stream>>>(K, Q, rns);

    scan_kernel<<<BB, 512, 0, stream>>>(Q, K, V, rns, O);

    dim3 ogrid(BT / 64, DD / 128);
    out_kernel<<<ogrid, 256, 0, stream>>>(O, Wo, bo, out);
}

// Round 6
// 1175.202 us; speedup vs baseline: 2.1139x; 2.1139x over previous
//
#include <hip/hip_runtime.h>
#include <math.h>

#define BB 4
#define TT 2048
#define DD 1024
#define HH 128
#define EPSF 1e-6f
#define BT (BB*TT)   // 8192
#define CC 128       // phase-2 chunk length
#define NCH (TT/CC)  // 16 chunks per batch

typedef float f32x2 __attribute__((ext_vector_type(2)));

// ---------------------------------------------------------------------------
// Projection: P[bt][h] = sum_d x[bt][d] * W[h][d] + bias[h]
// ---------------------------------------------------------------------------
__global__ __launch_bounds__(256) void proj_kernel(
    const float* __restrict__ x,
    const float* __restrict__ Wq, const float* __restrict__ bq,
    const float* __restrict__ Wk, const float* __restrict__ bk,
    const float* __restrict__ Wv, const float* __restrict__ bv,
    float* __restrict__ Q, float* __restrict__ K, float* __restrict__ V)
{
    const int which = blockIdx.y;
    const float* W    = (which == 0) ? Wq : (which == 1) ? Wk : Wv;
    const float* bias = (which == 0) ? bq : (which == 1) ? bk : bv;
    float* P          = (which == 0) ? Q  : (which == 1) ? K  : V;

    const int row0 = blockIdx.x * 64;

    __shared__ float xT[32][68];
    __shared__ float wT[32][132];

    const int tid = threadIdx.x;
    const int tx = tid & 15;
    const int ty = tid >> 4;

    float acc[4][8];
    #pragma unroll
    for (int i = 0; i < 4; i++)
        #pragma unroll
        for (int j = 0; j < 8; j++) acc[i][j] = 0.f;

    for (int k0 = 0; k0 < DD; k0 += 32) {
        #pragma unroll
        for (int l = 0; l < 2; l++) {
            int f = tid + l * 256;
            int r = f >> 3;
            int cg = f & 7;
            float4 v = *(const float4*)(x + (size_t)(row0 + r) * DD + k0 + cg * 4);
            xT[cg*4+0][r] = v.x; xT[cg*4+1][r] = v.y;
            xT[cg*4+2][r] = v.z; xT[cg*4+3][r] = v.w;
        }
        #pragma unroll
        for (int l = 0; l < 4; l++) {
            int f = tid + l * 256;
            int h = f >> 3;
            int cg = f & 7;
            float4 v = *(const float4*)(W + (size_t)h * DD + k0 + cg * 4);
            wT[cg*4+0][h] = v.x; wT[cg*4+1][h] = v.y;
            wT[cg*4+2][h] = v.z; wT[cg*4+3][h] = v.w;
        }
        __syncthreads();
        #pragma unroll
        for (int kk = 0; kk < 32; kk++) {
            float4 xv = *(const float4*)&xT[kk][ty * 4];
            float4 w0 = *(const float4*)&wT[kk][tx * 8];
            float4 w1 = *(const float4*)&wT[kk][tx * 8 + 4];
            float xa[4] = {xv.x, xv.y, xv.z, xv.w};
            float wa[8] = {w0.x, w0.y, w0.z, w0.w, w1.x, w1.y, w1.z, w1.w};
            #pragma unroll
            for (int i = 0; i < 4; i++)
                #pragma unroll
                for (int j = 0; j < 8; j++)
                    acc[i][j] += xa[i] * wa[j];
        }
        __syncthreads();
    }

    #pragma unroll
    for (int i = 0; i < 4; i++) {
        int row = row0 + ty * 4 + i;
        #pragma unroll
        for (int j = 0; j < 8; j++) acc[i][j] += bias[tx * 8 + j];
        float4 o0 = {acc[i][0], acc[i][1], acc[i][2], acc[i][3]};
        float4 o1 = {acc[i][4], acc[i][5], acc[i][6], acc[i][7]};
        *(float4*)(P + (size_t)row * HH + tx * 8)     = o0;
        *(float4*)(P + (size_t)row * HH + tx * 8 + 4) = o1;
    }
}

// ---------------------------------------------------------------------------
// Precompute per-step scalars: rns[row] = (1/(||k||+eps), k.q).
// ---------------------------------------------------------------------------
__global__ __launch_bounds__(256) void rns_kernel(
    const float* __restrict__ K, const float* __restrict__ Q,
    float2* __restrict__ rns)
{
    const int row  = blockIdx.x * 4 + (threadIdx.x >> 6);
    const int lane = threadIdx.x & 63;
    const float* kp = K + (size_t)row * HH;
    const float* qp = Q + (size_t)row * HH;
    float k0 = kp[lane], k1 = kp[lane + 64];
    float q0 = qp[lane], q1 = qp[lane + 64];
    float p2  = k0 * k0 + k1 * k1;
    float pkq = k0 * q0 + k1 * q1;
    #pragma unroll
    for (int off = 32; off; off >>= 1) {
        p2  += __shfl_xor(p2, off);
        pkq += __shfl_xor(pkq, off);
    }
    if (lane == 0) {
        float rn = 1.0f / (sqrtf(p2) + EPSF);
        rns[row] = make_float2(rn, pkq);
    }
}

// 8-lane butterfly sum, pure DPP/VALU (no DS pipe):
// xor1 = quad_perm[1,0,3,2], xor2 = quad_perm[2,3,0,1],
// cross-quad within the 8-lane group = ROW_HALF_MIRROR (0x141).
__device__ __forceinline__ float red8(float x) {
    x += __int_as_float(__builtin_amdgcn_mov_dpp(__float_as_int(x), 0xB1,  0xF, 0xF, true));
    x += __int_as_float(__builtin_amdgcn_mov_dpp(__float_as_int(x), 0x4E,  0xF, 0xF, true));
    x += __int_as_float(__builtin_amdgcn_mov_dpp(__float_as_int(x), 0x141, 0xF, 0xF, true));
    return x;
}

// ---------------------------------------------------------------------------
// Sequential scan v7: A-recurrence ONLY; emits alpha_t = s*rn*inv_d*praw.
// M is deferred to a parallel chunked phase (exact reassociation):
//   o_t = sum_{s<=t} (alpha_s . q_t) v_s.
// 512 threads; thread owns A rows {2*r2, 2*r2+1} x cols [o8*16, o8*16+16);
// r2 = tid>>3, o8 = tid&7. Per step per thread: 8 b128 LDS reads total
// (4 Aus + 4 k-refill) -- ~1/3 of v4's LDS traffic, the measured serial
// resource. 8-lane reductions are 3 chained DPP adds (no ds ops).
// Padded LDS layout: element e at (e>>4)*20 + (e&15); the 8 group starts
// hit bank-quads {0,20,8,28,16,4,24,12} -> a wave's 8-octant float4 reads
// cover all 32 banks exactly (conflict-free).
// ---------------------------------------------------------------------------
__global__ __launch_bounds__(512, 1) void scan_kernel(
    const float* __restrict__ K, const float2* __restrict__ rns,
    float* __restrict__ Alpha)
{
    const int b   = blockIdx.x;
    const int tid = threadIdx.x;
    const int r2  = tid >> 3;      // row pair 0..63
    const int o8  = tid & 7;       // column octant
    const int c0  = o8 * 16;
    const int r0  = 2 * r2, r1 = r0 + 1;

    __shared__ float Aus[2][8 * 20];   // praw broadcast (rows), padded
    __shared__ float kst[2][8 * 20];   // k staging (cols), padded

    f32x2 Ar0[8], Ar1[8];
    #pragma unroll
    for (int j = 0; j < 8; j++) {
        Ar0[j].x = (c0 + 2*j     == r0) ? 1.f : 0.f;
        Ar0[j].y = (c0 + 2*j + 1 == r0) ? 1.f : 0.f;
        Ar1[j].x = (c0 + 2*j     == r1) ? 1.f : 0.f;
        Ar1[j].y = (c0 + 2*j + 1 == r1) ? 1.f : 0.f;
    }

    const float* Kb = K + (size_t)b * TT * HH;
    float*       Ab = Alpha + (size_t)b * TT * HH;
    const float2* rns_b = rns + (size_t)b * TT;

    const int woff = (r0 >> 4) * 20 + (r0 & 15);  // r0 even -> 8B aligned
    const int roff = o8 * 20;

    const bool ldr = tid < 32;
    const int lpoff = (tid >> 2) * 20 + (tid & 3) * 4;

    float4 pld = {0.f, 0.f, 0.f, 0.f};
    if (ldr) {
        float4 d0 = *(const float4*)(Kb + tid * 4);
        *(float4*)&kst[0][lpoff] = d0;
        pld = *(const float4*)(Kb + HH + tid * 4);
    }
    float2 rs_cur = rns_b[0];
    float2 rs_nxt = rns_b[1];
    __syncthreads();

    f32x2 kk[8];
    #pragma unroll
    for (int j = 0; j < 4; j++) {
        float4 tk = *(const float4*)&kst[0][roff + 4 * j];
        kk[2*j]   = (f32x2){tk.x, tk.y};
        kk[2*j+1] = (f32x2){tk.z, tk.w};
    }

    for (int t = 0; t < TT; t++) {
        const int buf = t & 1, nbuf = buf ^ 1;

        // --- praw partials for my 2 rows over my 16 cols
        f32x2 p0 = {0.f, 0.f}, p1 = {0.f, 0.f};
        #pragma unroll
        for (int j = 0; j < 8; j++) {
            p0 += Ar0[j] * kk[j];
            p1 += Ar1[j] * kk[j];
        }
        float praw0 = red8(p0.x + p0.y);
        float praw1 = red8(p1.x + p1.y);
        if (o8 == 0) *(float2*)&Aus[buf][woff] = make_float2(praw0, praw1);

        // stage k for t+1; prefetch k for t+2
        if (ldr && t + 1 < TT) {
            *(float4*)&kst[nbuf][lpoff] = pld;
            if (t + 2 < TT)
                pld = *(const float4*)(Kb + (size_t)(t + 2) * HH + tid * 4);
        }

        __syncthreads();   // Aus[buf] + kst[nbuf] ready

        // --- read praw vector at my 16 cols
        f32x2 av[8];
        #pragma unroll
        for (int j = 0; j < 4; j++) {
            float4 ta = *(const float4*)&Aus[buf][roff + 4 * j];
            av[2*j]   = (f32x2){ta.x, ta.y};
            av[2*j+1] = (f32x2){ta.z, ta.w};
        }

        // --- pd = k . praw (local partial + 8-lane DPP reduce)
        f32x2 pdv = {0.f, 0.f};
        #pragma unroll
        for (int j = 0; j < 8; j++) pdv += av[j] * kk[j];
        float pd = red8(pdv.x + pdv.y);

        // refill kk for t+1 (kk regs dead after pd)
        #pragma unroll
        for (int j = 0; j < 4; j++) {
            float4 tk = *(const float4*)&kst[nbuf][roff + 4 * j];
            kk[2*j]   = (f32x2){tk.x, tk.y};
            kk[2*j+1] = (f32x2){tk.z, tk.w};
        }

        const float rn  = rs_cur.x, s = rs_cur.y;
        const float rn2 = rn * rn;
        const float inv_d = __builtin_amdgcn_rcpf(1.0f + rn2 * pd);
        const float cA = rn2 * inv_d;
        const float zs = s * rn * inv_d;
        if (o8 == 0)
            *(float2*)(Ab + (size_t)t * HH + r0) =
                make_float2(zs * praw0, zs * praw1);

        // --- rank-1 update of A only
        const f32x2 f0 = {cA * praw0, cA * praw0};
        const f32x2 f1 = {cA * praw1, cA * praw1};
        #pragma unroll
        for (int j = 0; j < 8; j++) {
            Ar0[j] -= f0 * av[j];
            Ar1[j] -= f1 * av[j];
        }

        rs_cur = rs_nxt;
        if (t + 2 < TT) rs_nxt = rns_b[t + 2];
    }
}

// ---------------------------------------------------------------------------
// Phase 2a: G[b][i] = V_chunk^T @ Alpha_chunk  (HxH), K = s over CC rows.
// grid (BB*NCH, 2); block computes 64 G-rows x 128 G-cols.
// ---------------------------------------------------------------------------
__global__ __launch_bounds__(256) void gram_kernel(
    const float* __restrict__ V, const float* __restrict__ Alpha,
    float* __restrict__ G)
{
    const int bi = blockIdx.x;                 // b*NCH + chunk
    const int r0 = blockIdx.y * 64;

    const float* Vc = V     + (size_t)bi * CC * HH;
    const float* Ac = Alpha + (size_t)bi * CC * HH;

    __shared__ float vT[32][68];    // [s][r]  (natural layout)
    __shared__ float aT[32][132];   // [s][c]

    const int tid = threadIdx.x;
    const int tx = tid & 15, ty = tid >> 4;

    float acc[4][8];
    #pragma unroll
    for (int i = 0; i < 4; i++)
        #pragma unroll
        for (int j = 0; j < 8; j++) acc[i][j] = 0.f;

    for (int s0 = 0; s0 < CC; s0 += 32) {
        #pragma unroll
        for (int l = 0; l < 2; l++) {
            int f = tid + l * 256;
            int sr = f >> 4, rc = f & 15;
            float4 v = *(const float4*)(Vc + (size_t)(s0 + sr) * HH + r0 + rc * 4);
            *(float4*)&vT[sr][rc * 4] = v;
        }
        #pragma unroll
        for (int l = 0; l < 4; l++) {
            int f = tid + l * 256;
            int sr = f >> 5, cc = f & 31;
            float4 v = *(const float4*)(Ac + (size_t)(s0 + sr) * HH + cc * 4);
            *(float4*)&aT[sr][cc * 4] = v;
        }
        __syncthreads();
        #pragma unroll
        for (int ss = 0; ss < 32; ss++) {
            float4 vv = *(const float4*)&vT[ss][ty * 4];
            float4 a0 = *(const float4*)&aT[ss][tx * 8];
            float4 a1 = *(const float4*)&aT[ss][tx * 8 + 4];
            float va[4] = {vv.x, vv.y, vv.z, vv.w};
            float aa[8] = {a0.x, a0.y, a0.z, a0.w, a1.x, a1.y, a1.z, a1.w};
            #pragma unroll
            for (int i = 0; i < 4; i++)
                #pragma unroll
                for (int j = 0; j < 8; j++)
                    acc[i][j] += va[i] * aa[j];
        }
        __syncthreads();
    }

    #pragma unroll
    for (int i = 0; i < 4; i++) {
        float* gp = G + ((size_t)bi * HH + r0 + ty * 4 + i) * HH + tx * 8;
        float4 o0 = {acc[i][0], acc[i][1], acc[i][2], acc[i][3]};
        float4 o1 = {acc[i][4], acc[i][5], acc[i][6], acc[i][7]};
        *(float4*)gp       = o0;
        *(float4*)(gp + 4) = o1;
    }
}

// ---------------------------------------------------------------------------
// Phase 2b: exclusive prefix over chunks: Mpre[b][i] = sum_{j<i} G[b][j].
// grid (BB, HH*HH/256).
// ---------------------------------------------------------------------------
__global__ __launch_bounds__(256) void prefix_kernel(
    const float* __restrict__ G, float* __restrict__ Mpre)
{
    const int b   = blockIdx.x;
    const int idx = blockIdx.y * 256 + threadIdx.x;
    float run = 0.f;
    for (int i = 0; i < NCH; i++) {
        size_t off = ((size_t)b * NCH + i) * HH * HH + idx;
        Mpre[off] = run;
        run += G[off];
    }
}

// ---------------------------------------------------------------------------
// Phase 2c: O_half = Q_half @ Mpre^T + tril(Q_half @ Alpha^T) @ V_chunk.
// grid (BB*NCH, 2); block = 256; handles 64 t-rows x 128 h-cols.
// ---------------------------------------------------------------------------
__global__ __launch_bounds__(256) void ochunk_kernel(
    const float* __restrict__ Q, const float* __restrict__ Alpha,
    const float* __restrict__ V, const float* __restrict__ Mpre,
    float* __restrict__ O)
{
    const int bi = blockIdx.x;
    const int t0 = blockIdx.y * 64;            // local t base within chunk

    const float* Qc = Q     + (size_t)bi * CC * HH;
    const float* Ac = Alpha + (size_t)bi * CC * HH;
    const float* Vc = V     + (size_t)bi * CC * HH;
    const float* Mp = Mpre  + (size_t)bi * HH * HH;
    float*       Oc = O     + (size_t)bi * CC * HH;

    __shared__ float S[64][132];     // masked scores
    __shared__ float xT[32][68];     // transposed Q staging
    __shared__ float wT[32][132];    // transposed Alpha/Mpre staging; V rows

    const int tid = threadIdx.x;
    const int tx = tid & 15, ty = tid >> 4;

    float acc[4][8];

    // ---- phase 1: S = Q_half @ Alpha^T (K = h)
    #pragma unroll
    for (int i = 0; i < 4; i++)
        #pragma unroll
        for (int j = 0; j < 8; j++) acc[i][j] = 0.f;
    for (int k0 = 0; k0 < HH; k0 += 32) {
        #pragma unroll
        for (int l = 0; l < 2; l++) {
            int f = tid + l * 256;
            int r = f >> 3, cg = f & 7;
            float4 v = *(const float4*)(Qc + (size_t)(t0 + r) * HH + k0 + cg * 4);
            xT[cg*4+0][r] = v.x; xT[cg*4+1][r] = v.y;
            xT[cg*4+2][r] = v.z; xT[cg*4+3][r] = v.w;
        }
        #pragma unroll
        for (int l = 0; l < 4; l++) {
            int f = tid + l * 256;
            int sr = f >> 3, cg = f & 7;
            float4 v = *(const float4*)(Ac + (size_t)sr * HH + k0 + cg * 4);
            wT[cg*4+0][sr] = v.x; wT[cg*4+1][sr] = v.y;
            wT[cg*4+2][sr] = v.z; wT[cg*4+3][sr] = v.w;
        }
        __syncthreads();
        #pragma unroll
        for (int kk = 0; kk < 32; kk++) {
            float4 xv = *(const float4*)&xT[kk][ty * 4];
            float4 w0 = *(const float4*)&wT[kk][tx * 8];
            float4 w1 = *(const float4*)&wT[kk][tx * 8 + 4];
            float xa[4] = {xv.x, xv.y, xv.z, xv.w};
            float wa[8] = {w0.x, w0.y, w0.z, w0.w, w1.x, w1.y, w1.z, w1.w};
            #pragma unroll
            for (int i = 0; i < 4; i++)
                #pragma unroll
                for (int j = 0; j < 8; j++)
                    acc[i][j] += xa[i] * wa[j];
        }
        __syncthreads();
    }
    // write causal-masked S (s <= t inclusive: M is post-update at step t)
    #pragma unroll
    for (int i = 0; i < 4; i++) {
        int tl = t0 + ty * 4 + i;
        float m[8];
        #pragma unroll
        for (int j = 0; j < 8; j++)
            m[j] = (tx * 8 + j <= tl) ? acc[i][j] : 0.f;
        float4 o0 = {m[0], m[1], m[2], m[3]};
        float4 o1 = {m[4], m[5], m[6], m[7]};
        *(float4*)&S[ty*4+i][tx*8]     = o0;
        *(float4*)&S[ty*4+i][tx*8 + 4] = o1;
    }

    // ---- phase 2: acc = Q_half @ Mpre^T (K = h')
    #pragma unroll
    for (int i = 0; i < 4; i++)
        #pragma unroll
        for (int j = 0; j < 8; j++) acc[i][j] = 0.f;
    for (int k0 = 0; k0 < HH; k0 += 32) {
        #pragma unroll
        for (int l = 0; l < 2; l++) {
            int f = tid + l * 256;
            int r = f >> 3, cg = f & 7;
            float4 v = *(const float4*)(Qc + (size_t)(t0 + r) * HH + k0 + cg * 4);
            xT[cg*4+0][r] = v.x; xT[cg*4+1][r] = v.y;
            xT[cg*4+2][r] = v.z; xT[cg*4+3][r] = v.w;
        }
        #pragma unroll
        for (int l = 0; l < 4; l++) {
            int f = tid + l * 256;
            int h = f >> 3, cg = f & 7;
            float4 v = *(const float4*)(Mp + (size_t)h * HH + k0 + cg * 4);
            wT[cg*4+0][h] = v.x; wT[cg*4+1][h] = v.y;
            wT[cg*4+2][h] = v.z; wT[cg*4+3][h] = v.w;
        }
        __syncthreads();
        #pragma unroll
        for (int kk = 0; kk < 32; kk++) {
            float4 xv = *(const float4*)&xT[kk][ty * 4];
            float4 w0 = *(const float4*)&wT[kk][tx * 8];
            float4 w1 = *(const float4*)&wT[kk][tx * 8 + 4];
            float xa[4] = {xv.x, xv.y, xv.z, xv.w};
            float wa[8] = {w0.x, w0.y, w0.z, w0.w, w1.x, w1.y, w1.z, w1.w};
            #pragma unroll
            for (int i = 0; i < 4; i++)
                #pragma unroll
                for (int j = 0; j < 8; j++)
                    acc[i][j] += xa[i] * wa[j];
        }
        __syncthreads();
    }

    // ---- phase 3: acc += S @ V (K = s); wT reused for V rows (natural)
    for (int s0 = 0; s0 < CC; s0 += 32) {
        #pragma unroll
        for (int l = 0; l < 4; l++) {
            int f = tid + l * 256;
            int sr = f >> 5, cc = f & 31;
            float4 v = *(const float4*)(Vc + (size_t)(s0 + sr) * HH + cc * 4);
            *(float4*)&wT[sr][cc * 4] = v;
        }
        __syncthreads();
        #pragma unroll
        for (int ss = 0; ss < 32; ss++) {
            float4 w0 = *(const float4*)&wT[ss][tx * 8];
            float4 w1 = *(const float4*)&wT[ss][tx * 8 + 4];
            float wa[8] = {w0.x, w0.y, w0.z, w0.w, w1.x, w1.y, w1.z, w1.w};
            float sv[4];
            #pragma unroll
            for (int i = 0; i < 4; i++) sv[i] = S[ty*4+i][s0 + ss];
            #pragma unroll
            for (int i = 0; i < 4; i++)
                #pragma unroll
                for (int j = 0; j < 8; j++)
                    acc[i][j] += sv[i] * wa[j];
        }
        __syncthreads();
    }

    // ---- write O
    #pragma unroll
    for (int i = 0; i < 4; i++) {
        float* op = Oc + (size_t)(t0 + ty * 4 + i) * HH + tx * 8;
        float4 o0 = {acc[i][0], acc[i][1], acc[i][2], acc[i][3]};
        float4 o1 = {acc[i][4], acc[i][5], acc[i][6], acc[i][7]};
        *(float4*)op       = o0;
        *(float4*)(op + 4) = o1;
    }
}

// ---------------------------------------------------------------------------
// Output: out[bt][d] = sum_h O[bt][h] * Wo[d][h] + bo[d]
// ---------------------------------------------------------------------------
__global__ __launch_bounds__(256) void out_kernel(
    const float* __restrict__ O, const float* __restrict__ Wo,
    const float* __restrict__ bo, float* __restrict__ out)
{
    const int row0 = blockIdx.x * 64;
    const int d0   = blockIdx.y * 128;

    __shared__ float oT[32][68];
    __shared__ float woT[32][132];

    const int tid = threadIdx.x;
    const int tx = tid & 15;
    const int ty = tid >> 4;

    float acc[4][8];
    #pragma unroll
    for (int i = 0; i < 4; i++)
        #pragma unroll
        for (int j = 0; j < 8; j++) acc[i][j] = 0.f;

    for (int k0 = 0; k0 < HH; k0 += 32) {
        #pragma unroll
        for (int l = 0; l < 2; l++) {
            int f = tid + l * 256;
            int r = f >> 3;
            int cg = f & 7;
            float4 v = *(const float4*)(O + (size_t)(row0 + r) * HH + k0 + cg * 4);
            oT[cg*4+0][r] = v.x; oT[cg*4+1][r] = v.y;
            oT[cg*4+2][r] = v.z; oT[cg*4+3][r] = v.w;
        }
        #pragma unroll
        for (int l = 0; l < 4; l++) {
            int f = tid + l * 256;
            int d = f >> 3;
            int cg = f & 7;
            float4 v = *(const float4*)(Wo + (size_t)(d0 + d) * HH + k0 + cg * 4);
            woT[cg*4+0][d] = v.x; woT[cg*4+1][d] = v.y;
            woT[cg*4+2][d] = v.z; woT[cg*4+3][d] = v.w;
        }
        __syncthreads();
        #pragma unroll
        for (int kk = 0; kk < 32; kk++) {
            float4 ov = *(const float4*)&oT[kk][ty * 4];
            float4 w0 = *(const float4*)&woT[kk][tx * 8];
            float4 w1 = *(const float4*)&woT[kk][tx * 8 + 4];
            float oa[4] = {ov.x, ov.y, ov.z, ov.w};
            float wa[8] = {w0.x, w0.y, w0.z, w0.w, w1.x, w1.y, w1.z, w1.w};
            #pragma unroll
            for (int i = 0; i < 4; i++)
                #pragma unroll
                for (int j = 0; j < 8; j++)
                    acc[i][j] += oa[i] * wa[j];
        }
        __syncthreads();
    }

    #pragma unroll
    for (int i = 0; i < 4; i++) {
        int row = row0 + ty * 4 + i;
        #pragma unroll
        for (int j = 0; j < 8; j++) acc[i][j] += bo[d0 + tx * 8 + j];
        float4 o0 = {acc[i][0], acc[i][1], acc[i][2], acc[i][3]};
        float4 o1 = {acc[i][4], acc[i][5], acc[i][6], acc[i][7]};
        *(float4*)(out + (size_t)row * DD + d0 + tx * 8)     = o0;
        *(float4*)(out + (size_t)row * DD + d0 + tx * 8 + 4) = o1;
    }
}

extern "C" void kernel_launch(void* const* d_in, const int* in_sizes, int n_in,
                              void* d_out, int out_size, void* d_ws, size_t ws_size,
                              hipStream_t stream) {
    const float* x  = (const float*)d_in[0];
    const float* Wq = (const float*)d_in[1];
    const float* bq = (const float*)d_in[2];
    const float* Wk = (const float*)d_in[3];
    const float* bk = (const float*)d_in[4];
    const float* Wv = (const float*)d_in[5];
    const float* bv = (const float*)d_in[6];
    const float* Wo = (const float*)d_in[7];
    const float* bo = (const float*)d_in[8];
    float* out = (float*)d_out;

    float* ws = (float*)d_ws;
    float* Q = ws;
    float* K = ws + (size_t)BT * HH;
    float* V = ws + (size_t)2 * BT * HH;
    float* O = ws + (size_t)3 * BT * HH;

    // scratch that lives in d_out (32 MB); all consumed before out_kernel:
    //   rns   @ 0      (64 KB)
    //   Alpha @ 1 MB   (4 MB)
    //   G     @ 8 MB   (4 MB)
    //   Mpre  @ 12 MB  (4 MB)
    float*  db    = (float*)d_out;
    float2* rns   = (float2*)db;
    float*  Alpha = db + (1u << 18);        // 1 MB / 4
    float*  G     = db + (1u << 21);        // 8 MB / 4
    float*  Mpre  = db + 3u * (1u << 20);   // 12 MB / 4

    dim3 pgrid(BT / 64, 3);
    proj_kernel<<<pgrid, 256, 0, stream>>>(x, Wq, bq, Wk, bk, Wv, bv, Q, K, V);

    rns_kernel<<<BT / 4, 256, 0, stream>>>(K, Q, rns);

    scan_kernel<<<BB, 512, 0, stream>>>(K, rns, Alpha);

    dim3 ggrid(BB * NCH, 2);
    gram_kernel<<<ggrid, 256, 0, stream>>>(V, Alpha, G);

    dim3 fgrid(BB, HH * HH / 256);
    prefix_kernel<<<fgrid, 256, 0, stream>>>(G, Mpre);

    dim3 cgrid(BB * NCH, 2);
    ochunk_kernel<<<cgrid, 256, 0, stream>>>(Q, Alpha, V, Mpre, O);

    dim3 ogrid(BT / 64, DD / 128);
    out_kernel<<<ogrid, 256, 0, stream>>>(O, Wo, bo, out);
}

// Round 7
// 1119.138 us; speedup vs baseline: 2.2198x; 1.0501x over previous
//
#include <hip/hip_runtime.h>
#include <math.h>

#define BB 4
#define TT 2048
#define DD 1024
#define HH 128
#define EPSF 1e-6f
#define BT (BB*TT)   // 8192
#define CC 128       // phase-2 chunk length
#define NCH (TT/CC)  // 16 chunks per batch
#define NI (TT/2)    // 1024 double-steps

typedef float f32x2 __attribute__((ext_vector_type(2)));

// ---------------------------------------------------------------------------
// Projection: P[bt][h] = sum_d x[bt][d] * W[h][d] + bias[h]
// ---------------------------------------------------------------------------
__global__ __launch_bounds__(256) void proj_kernel(
    const float* __restrict__ x,
    const float* __restrict__ Wq, const float* __restrict__ bq,
    const float* __restrict__ Wk, const float* __restrict__ bk,
    const float* __restrict__ Wv, const float* __restrict__ bv,
    float* __restrict__ Q, float* __restrict__ K, float* __restrict__ V)
{
    const int which = blockIdx.y;
    const float* W    = (which == 0) ? Wq : (which == 1) ? Wk : Wv;
    const float* bias = (which == 0) ? bq : (which == 1) ? bk : bv;
    float* P          = (which == 0) ? Q  : (which == 1) ? K  : V;

    const int row0 = blockIdx.x * 64;

    __shared__ float xT[32][68];
    __shared__ float wT[32][132];

    const int tid = threadIdx.x;
    const int tx = tid & 15;
    const int ty = tid >> 4;

    float acc[4][8];
    #pragma unroll
    for (int i = 0; i < 4; i++)
        #pragma unroll
        for (int j = 0; j < 8; j++) acc[i][j] = 0.f;

    for (int k0 = 0; k0 < DD; k0 += 32) {
        #pragma unroll
        for (int l = 0; l < 2; l++) {
            int f = tid + l * 256;
            int r = f >> 3;
            int cg = f & 7;
            float4 v = *(const float4*)(x + (size_t)(row0 + r) * DD + k0 + cg * 4);
            xT[cg*4+0][r] = v.x; xT[cg*4+1][r] = v.y;
            xT[cg*4+2][r] = v.z; xT[cg*4+3][r] = v.w;
        }
        #pragma unroll
        for (int l = 0; l < 4; l++) {
            int f = tid + l * 256;
            int h = f >> 3;
            int cg = f & 7;
            float4 v = *(const float4*)(W + (size_t)h * DD + k0 + cg * 4);
            wT[cg*4+0][h] = v.x; wT[cg*4+1][h] = v.y;
            wT[cg*4+2][h] = v.z; wT[cg*4+3][h] = v.w;
        }
        __syncthreads();
        #pragma unroll
        for (int kk = 0; kk < 32; kk++) {
            float4 xv = *(const float4*)&xT[kk][ty * 4];
            float4 w0 = *(const float4*)&wT[kk][tx * 8];
            float4 w1 = *(const float4*)&wT[kk][tx * 8 + 4];
            float xa[4] = {xv.x, xv.y, xv.z, xv.w};
            float wa[8] = {w0.x, w0.y, w0.z, w0.w, w1.x, w1.y, w1.z, w1.w};
            #pragma unroll
            for (int i = 0; i < 4; i++)
                #pragma unroll
                for (int j = 0; j < 8; j++)
                    acc[i][j] += xa[i] * wa[j];
        }
        __syncthreads();
    }

    #pragma unroll
    for (int i = 0; i < 4; i++) {
        int row = row0 + ty * 4 + i;
        #pragma unroll
        for (int j = 0; j < 8; j++) acc[i][j] += bias[tx * 8 + j];
        float4 o0 = {acc[i][0], acc[i][1], acc[i][2], acc[i][3]};
        float4 o1 = {acc[i][4], acc[i][5], acc[i][6], acc[i][7]};
        *(float4*)(P + (size_t)row * HH + tx * 8)     = o0;
        *(float4*)(P + (size_t)row * HH + tx * 8 + 4) = o1;
    }
}

// ---------------------------------------------------------------------------
// Precompute per-step scalars: rns[row] = (1/(||k||+eps), k.q).
// ---------------------------------------------------------------------------
__global__ __launch_bounds__(256) void rns_kernel(
    const float* __restrict__ K, const float* __restrict__ Q,
    float2* __restrict__ rns)
{
    const int row  = blockIdx.x * 4 + (threadIdx.x >> 6);
    const int lane = threadIdx.x & 63;
    const float* kp = K + (size_t)row * HH;
    const float* qp = Q + (size_t)row * HH;
    float k0 = kp[lane], k1 = kp[lane + 64];
    float q0 = qp[lane], q1 = qp[lane + 64];
    float p2  = k0 * k0 + k1 * k1;
    float pkq = k0 * q0 + k1 * q1;
    #pragma unroll
    for (int off = 32; off; off >>= 1) {
        p2  += __shfl_xor(p2, off);
        pkq += __shfl_xor(pkq, off);
    }
    if (lane == 0) {
        float rn = 1.0f / (sqrtf(p2) + EPSF);
        rns[row] = make_float2(rn, pkq);
    }
}

// 8-lane butterfly sum, pure DPP/VALU (no DS pipe):
// xor1 = quad_perm[1,0,3,2], xor2 = quad_perm[2,3,0,1],
// cross-quad within the 8-lane group = ROW_HALF_MIRROR (0x141).
__device__ __forceinline__ float red8(float x) {
    x += __int_as_float(__builtin_amdgcn_mov_dpp(__float_as_int(x), 0xB1,  0xF, 0xF, true));
    x += __int_as_float(__builtin_amdgcn_mov_dpp(__float_as_int(x), 0x4E,  0xF, 0xF, true));
    x += __int_as_float(__builtin_amdgcn_mov_dpp(__float_as_int(x), 0x141, 0xF, 0xF, true));
    return x;
}

// ---------------------------------------------------------------------------
// Sequential scan v8: A-only recurrence, TWO steps per barrier (rank-2
// Sherman-Morrison, v6's verified algebra minus all M terms).
// Emits alpha_t = s_t*rn_t*inv_d_t * (A_{t-1,updated} k_t).
//
// 512 threads; thread owns A rows {r0,r1} x cols [o8*16, o8*16+16);
// r2 = tid>>3, o8 = tid&7, r0 = 2*r2.
// Per double-step: pre-barrier y1 = A k1, y2 = A k2 (4 red8), broadcast;
// post-barrier read y1,y2 at my cols, 3 dots e11=k1.y1 e21=k2.y1 e22=k2.y2,
// scalars i1/beta/i2, rank-2 update. Halves barrier + LDS-latency + scalar
// chain events per step vs v7 for ~15% more VALU; LDS traffic per PAIR of
// steps equals v7's per-step traffic (M-state is gone, unlike v6).
// Padded layout: element e at (e>>4)*20 + (e&15) -> conflict-free.
// ---------------------------------------------------------------------------
__global__ __launch_bounds__(512, 1) void scan_kernel(
    const float* __restrict__ K, const float2* __restrict__ rns,
    float* __restrict__ Alpha)
{
    const int b   = blockIdx.x;
    const int tid = threadIdx.x;
    const int r2  = tid >> 3;      // row pair 0..63
    const int o8  = tid & 7;       // column octant
    const int c0  = o8 * 16;
    const int r0  = 2 * r2, r1 = r0 + 1;

    __shared__ float Ybc[2][2][8 * 20];   // [buf][y1/y2] broadcast, padded
    __shared__ float kst[2][2][8 * 20];   // [buf][k1/k2] staging, padded

    f32x2 Ar0[8], Ar1[8];
    #pragma unroll
    for (int j = 0; j < 8; j++) {
        Ar0[j].x = (c0 + 2*j     == r0) ? 1.f : 0.f;
        Ar0[j].y = (c0 + 2*j + 1 == r0) ? 1.f : 0.f;
        Ar1[j].x = (c0 + 2*j     == r1) ? 1.f : 0.f;
        Ar1[j].y = (c0 + 2*j + 1 == r1) ? 1.f : 0.f;
    }

    const float* Kb = K + (size_t)b * TT * HH;
    float*       Ab = Alpha + (size_t)b * TT * HH;
    const float2* rns_b = rns + (size_t)b * TT;

    const int woff = (r0 >> 4) * 20 + (r0 & 15);  // r0 even -> 8B aligned
    const int roff = o8 * 20;

    // loaders: 64 threads, one float4 each per double-step.
    const bool ldr    = tid < 64;
    const int  whichk = (tid >> 5) & 1;           // 0=k1(even t) 1=k2(odd t)
    const int  l32    = tid & 31;
    const int  lpoff  = (l32 >> 2) * 20 + (l32 & 3) * 4;

    float4 pld = {0.f, 0.f, 0.f, 0.f};
    if (ldr) {
        float4 d0 = *(const float4*)(Kb + (size_t)whichk * HH + l32 * 4);
        *(float4*)&kst[0][whichk][lpoff] = d0;
        pld = *(const float4*)(Kb + (size_t)(2 + whichk) * HH + l32 * 4);
    }
    float4 rs_cur = ((const float4*)rns_b)[0];
    float4 rs_nxt = ((const float4*)rns_b)[1];
    __syncthreads();   // kst[0] ready

    f32x2 k1[8], k2[8];
    #pragma unroll
    for (int j = 0; j < 4; j++) {
        float4 t1 = *(const float4*)&kst[0][0][roff + 4 * j];
        float4 t2 = *(const float4*)&kst[0][1][roff + 4 * j];
        k1[2*j] = (f32x2){t1.x, t1.y}; k1[2*j+1] = (f32x2){t1.z, t1.w};
        k2[2*j] = (f32x2){t2.x, t2.y}; k2[2*j+1] = (f32x2){t2.z, t2.w};
    }

    for (int i = 0; i < NI; ++i) {
        const int yb = i & 1;
        const int nk = (i + 1) & 1;

        // --- y1 = A k1, y2 = A k2 partials for my 2 rows over my 16 cols
        f32x2 y10 = {0,0}, y11 = {0,0}, y20 = {0,0}, y21 = {0,0};
        #pragma unroll
        for (int j = 0; j < 8; j++) {
            y10 += Ar0[j] * k1[j];
            y11 += Ar1[j] * k1[j];
            y20 += Ar0[j] * k2[j];
            y21 += Ar1[j] * k2[j];
        }
        float y1r0 = red8(y10.x + y10.y);
        float y1r1 = red8(y11.x + y11.y);
        float y2r0 = red8(y20.x + y20.y);
        float y2r1 = red8(y21.x + y21.y);
        if (o8 == 0) {
            *(float2*)&Ybc[yb][0][woff] = make_float2(y1r0, y1r1);
            *(float2*)&Ybc[yb][1][woff] = make_float2(y2r0, y2r1);
        }

        // stage k-pair for iter i+1; prefetch pair for i+2
        if (ldr && i + 1 < NI) {
            *(float4*)&kst[nk][whichk][lpoff] = pld;
            if (i + 2 < NI)
                pld = *(const float4*)(Kb + (size_t)(2*(i+2) + whichk) * HH + l32 * 4);
        }

        __syncthreads();   // Ybc[yb] + kst[nk] ready

        // --- read y1,y2 vectors at my 16 cols
        f32x2 av1[8], av2[8];
        #pragma unroll
        for (int j = 0; j < 4; j++) {
            float4 t1 = *(const float4*)&Ybc[yb][0][roff + 4 * j];
            float4 t2 = *(const float4*)&Ybc[yb][1][roff + 4 * j];
            av1[2*j] = (f32x2){t1.x, t1.y}; av1[2*j+1] = (f32x2){t1.z, t1.w};
            av2[2*j] = (f32x2){t2.x, t2.y}; av2[2*j+1] = (f32x2){t2.z, t2.w};
        }

        // --- e11 = k1.y1, e21 = k2.y1, e22 = k2.y2 (partials + red8)
        f32x2 e11v = {0,0}, e21v = {0,0}, e22v = {0,0};
        #pragma unroll
        for (int j = 0; j < 8; j++) {
            e11v += av1[j] * k1[j];
            e21v += av1[j] * k2[j];
            e22v += av2[j] * k2[j];
        }
        float e11 = red8(e11v.x + e11v.y);
        float e21 = red8(e21v.x + e21v.y);
        float e22 = red8(e22v.x + e22v.y);

        // refill k1,k2 for iter i+1 (regs dead after the dots)
        #pragma unroll
        for (int j = 0; j < 4; j++) {
            float4 t1 = *(const float4*)&kst[nk][0][roff + 4 * j];
            float4 t2 = *(const float4*)&kst[nk][1][roff + 4 * j];
            k1[2*j] = (f32x2){t1.x, t1.y}; k1[2*j+1] = (f32x2){t1.z, t1.w};
            k2[2*j] = (f32x2){t2.x, t2.y}; k2[2*j+1] = (f32x2){t2.z, t2.w};
        }

        // --- scalars (exact rank-2 recurrence, v6-verified)
        const float rn1 = rs_cur.x, s1 = rs_cur.y;
        const float rn2 = rs_cur.z, s2 = rs_cur.w;
        const float rn1sq = rn1 * rn1;
        const float rn2sq = rn2 * rn2;
        const float i1   = __builtin_amdgcn_rcpf(1.0f + rn1sq * e11);
        const float beta = rn1sq * e21 * i1;
        const float i2   = __builtin_amdgcn_rcpf(1.0f + rn2sq * (e22 - beta * e21));
        const float p2r0 = y2r0 - beta * y1r0;
        const float p2r1 = y2r1 - beta * y1r1;
        const float za1  = s1 * rn1 * i1;
        const float za2  = s2 * rn2 * i2;
        if (o8 == 0) {
            *(float2*)(Ab + (size_t)(2*i)     * HH + r0) =
                make_float2(za1 * y1r0, za1 * y1r1);
            *(float2*)(Ab + (size_t)(2*i + 1) * HH + r0) =
                make_float2(za2 * p2r0, za2 * p2r1);
        }

        // --- rank-2 update of A
        const float cA1 = rn1sq * i1, cA2 = rn2sq * i2;
        const f32x2 u10 = {cA1 * y1r0, cA1 * y1r0};
        const f32x2 u11 = {cA1 * y1r1, cA1 * y1r1};
        const f32x2 u20 = {cA2 * p2r0, cA2 * p2r0};
        const f32x2 u21 = {cA2 * p2r1, cA2 * p2r1};
        const f32x2 bbv = {beta, beta};
        #pragma unroll
        for (int j = 0; j < 8; j++) {
            f32x2 pp = av2[j] - bbv * av1[j];
            Ar0[j] = Ar0[j] - u10 * av1[j] - u20 * pp;
            Ar1[j] = Ar1[j] - u11 * av1[j] - u21 * pp;
        }

        rs_cur = rs_nxt;
        if (i + 2 < NI) rs_nxt = ((const float4*)rns_b)[i + 2];
    }
}

// ---------------------------------------------------------------------------
// Phase 2a: G[b][i] = V_chunk^T @ Alpha_chunk  (HxH), K = s over CC rows.
// ---------------------------------------------------------------------------
__global__ __launch_bounds__(256) void gram_kernel(
    const float* __restrict__ V, const float* __restrict__ Alpha,
    float* __restrict__ G)
{
    const int bi = blockIdx.x;                 // b*NCH + chunk
    const int r0 = blockIdx.y * 64;

    const float* Vc = V     + (size_t)bi * CC * HH;
    const float* Ac = Alpha + (size_t)bi * CC * HH;

    __shared__ float vT[32][68];
    __shared__ float aT[32][132];

    const int tid = threadIdx.x;
    const int tx = tid & 15, ty = tid >> 4;

    float acc[4][8];
    #pragma unroll
    for (int i = 0; i < 4; i++)
        #pragma unroll
        for (int j = 0; j < 8; j++) acc[i][j] = 0.f;

    for (int s0 = 0; s0 < CC; s0 += 32) {
        #pragma unroll
        for (int l = 0; l < 2; l++) {
            int f = tid + l * 256;
            int sr = f >> 4, rc = f & 15;
            float4 v = *(const float4*)(Vc + (size_t)(s0 + sr) * HH + r0 + rc * 4);
            *(float4*)&vT[sr][rc * 4] = v;
        }
        #pragma unroll
        for (int l = 0; l < 4; l++) {
            int f = tid + l * 256;
            int sr = f >> 5, cc = f & 31;
            float4 v = *(const float4*)(Ac + (size_t)(s0 + sr) * HH + cc * 4);
            *(float4*)&aT[sr][cc * 4] = v;
        }
        __syncthreads();
        #pragma unroll
        for (int ss = 0; ss < 32; ss++) {
            float4 vv = *(const float4*)&vT[ss][ty * 4];
            float4 a0 = *(const float4*)&aT[ss][tx * 8];
            float4 a1 = *(const float4*)&aT[ss][tx * 8 + 4];
            float va[4] = {vv.x, vv.y, vv.z, vv.w};
            float aa[8] = {a0.x, a0.y, a0.z, a0.w, a1.x, a1.y, a1.z, a1.w};
            #pragma unroll
            for (int i = 0; i < 4; i++)
                #pragma unroll
                for (int j = 0; j < 8; j++)
                    acc[i][j] += va[i] * aa[j];
        }
        __syncthreads();
    }

    #pragma unroll
    for (int i = 0; i < 4; i++) {
        float* gp = G + ((size_t)bi * HH + r0 + ty * 4 + i) * HH + tx * 8;
        float4 o0 = {acc[i][0], acc[i][1], acc[i][2], acc[i][3]};
        float4 o1 = {acc[i][4], acc[i][5], acc[i][6], acc[i][7]};
        *(float4*)gp       = o0;
        *(float4*)(gp + 4) = o1;
    }
}

// ---------------------------------------------------------------------------
// Phase 2b: exclusive prefix over chunks: Mpre[b][i] = sum_{j<i} G[b][j].
// ---------------------------------------------------------------------------
__global__ __launch_bounds__(256) void prefix_kernel(
    const float* __restrict__ G, float* __restrict__ Mpre)
{
    const int b   = blockIdx.x;
    const int idx = blockIdx.y * 256 + threadIdx.x;
    float run = 0.f;
    for (int i = 0; i < NCH; i++) {
        size_t off = ((size_t)b * NCH + i) * HH * HH + idx;
        Mpre[off] = run;
        run += G[off];
    }
}

// ---------------------------------------------------------------------------
// Phase 2c: O_half = Q_half @ Mpre^T + tril(Q_half @ Alpha^T) @ V_chunk.
// ---------------------------------------------------------------------------
__global__ __launch_bounds__(256) void ochunk_kernel(
    const float* __restrict__ Q, const float* __restrict__ Alpha,
    const float* __restrict__ V, const float* __restrict__ Mpre,
    float* __restrict__ O)
{
    const int bi = blockIdx.x;
    const int t0 = blockIdx.y * 64;            // local t base within chunk

    const float* Qc = Q     + (size_t)bi * CC * HH;
    const float* Ac = Alpha + (size_t)bi * CC * HH;
    const float* Vc = V     + (size_t)bi * CC * HH;
    const float* Mp = Mpre  + (size_t)bi * HH * HH;
    float*       Oc = O     + (size_t)bi * CC * HH;

    __shared__ float S[64][132];
    __shared__ float xT[32][68];
    __shared__ float wT[32][132];

    const int tid = threadIdx.x;
    const int tx = tid & 15, ty = tid >> 4;

    float acc[4][8];

    // ---- phase 1: S = Q_half @ Alpha^T (K = h)
    #pragma unroll
    for (int i = 0; i < 4; i++)
        #pragma unroll
        for (int j = 0; j < 8; j++) acc[i][j] = 0.f;
    for (int k0 = 0; k0 < HH; k0 += 32) {
        #pragma unroll
        for (int l = 0; l < 2; l++) {
            int f = tid + l * 256;
            int r = f >> 3, cg = f & 7;
            float4 v = *(const float4*)(Qc + (size_t)(t0 + r) * HH + k0 + cg * 4);
            xT[cg*4+0][r] = v.x; xT[cg*4+1][r] = v.y;
            xT[cg*4+2][r] = v.z; xT[cg*4+3][r] = v.w;
        }
        #pragma unroll
        for (int l = 0; l < 4; l++) {
            int f = tid + l * 256;
            int sr = f >> 3, cg = f & 7;
            float4 v = *(const float4*)(Ac + (size_t)sr * HH + k0 + cg * 4);
            wT[cg*4+0][sr] = v.x; wT[cg*4+1][sr] = v.y;
            wT[cg*4+2][sr] = v.z; wT[cg*4+3][sr] = v.w;
        }
        __syncthreads();
        #pragma unroll
        for (int kk = 0; kk < 32; kk++) {
            float4 xv = *(const float4*)&xT[kk][ty * 4];
            float4 w0 = *(const float4*)&wT[kk][tx * 8];
            float4 w1 = *(const float4*)&wT[kk][tx * 8 + 4];
            float xa[4] = {xv.x, xv.y, xv.z, xv.w};
            float wa[8] = {w0.x, w0.y, w0.z, w0.w, w1.x, w1.y, w1.z, w1.w};
            #pragma unroll
            for (int i = 0; i < 4; i++)
                #pragma unroll
                for (int j = 0; j < 8; j++)
                    acc[i][j] += xa[i] * wa[j];
        }
        __syncthreads();
    }
    #pragma unroll
    for (int i = 0; i < 4; i++) {
        int tl = t0 + ty * 4 + i;
        float m[8];
        #pragma unroll
        for (int j = 0; j < 8; j++)
            m[j] = (tx * 8 + j <= tl) ? acc[i][j] : 0.f;
        float4 o0 = {m[0], m[1], m[2], m[3]};
        float4 o1 = {m[4], m[5], m[6], m[7]};
        *(float4*)&S[ty*4+i][tx*8]     = o0;
        *(float4*)&S[ty*4+i][tx*8 + 4] = o1;
    }

    // ---- phase 2: acc = Q_half @ Mpre^T (K = h')
    #pragma unroll
    for (int i = 0; i < 4; i++)
        #pragma unroll
        for (int j = 0; j < 8; j++) acc[i][j] = 0.f;
    for (int k0 = 0; k0 < HH; k0 += 32) {
        #pragma unroll
        for (int l = 0; l < 2; l++) {
            int f = tid + l * 256;
            int r = f >> 3, cg = f & 7;
            float4 v = *(const float4*)(Qc + (size_t)(t0 + r) * HH + k0 + cg * 4);
            xT[cg*4+0][r] = v.x; xT[cg*4+1][r] = v.y;
            xT[cg*4+2][r] = v.z; xT[cg*4+3][r] = v.w;
        }
        #pragma unroll
        for (int l = 0; l < 4; l++) {
            int f = tid + l * 256;
            int h = f >> 3, cg = f & 7;
            float4 v = *(const float4*)(Mp + (size_t)h * HH + k0 + cg * 4);
            wT[cg*4+0][h] = v.x; wT[cg*4+1][h] = v.y;
            wT[cg*4+2][h] = v.z; wT[cg*4+3][h] = v.w;
        }
        __syncthreads();
        #pragma unroll
        for (int kk = 0; kk < 32; kk++) {
            float4 xv = *(const float4*)&xT[kk][ty * 4];
            float4 w0 = *(const float4*)&wT[kk][tx * 8];
            float4 w1 = *(const float4*)&wT[kk][tx * 8 + 4];
            float xa[4] = {xv.x, xv.y, xv.z, xv.w};
            float wa[8] = {w0.x, w0.y, w0.z, w0.w, w1.x, w1.y, w1.z, w1.w};
            #pragma unroll
            for (int i = 0; i < 4; i++)
                #pragma unroll
                for (int j = 0; j < 8; j++)
                    acc[i][j] += xa[i] * wa[j];
        }
        __syncthreads();
    }

    // ---- phase 3: acc += S @ V (K = s)
    for (int s0 = 0; s0 < CC; s0 += 32) {
        #pragma unroll
        for (int l = 0; l < 4; l++) {
            int f = tid + l * 256;
            int sr = f >> 5, cc = f & 31;
            float4 v = *(const float4*)(Vc + (size_t)(s0 + sr) * HH + cc * 4);
            *(float4*)&wT[sr][cc * 4] = v;
        }
        __syncthreads();
        #pragma unroll
        for (int ss = 0; ss < 32; ss++) {
            float4 w0 = *(const float4*)&wT[ss][tx * 8];
            float4 w1 = *(const float4*)&wT[ss][tx * 8 + 4];
            float wa[8] = {w0.x, w0.y, w0.z, w0.w, w1.x, w1.y, w1.z, w1.w};
            float sv[4];
            #pragma unroll
            for (int i = 0; i < 4; i++) sv[i] = S[ty*4+i][s0 + ss];
            #pragma unroll
            for (int i = 0; i < 4; i++)
                #pragma unroll
                for (int j = 0; j < 8; j++)
                    acc[i][j] += sv[i] * wa[j];
        }
        __syncthreads();
    }

    #pragma unroll
    for (int i = 0; i < 4; i++) {
        float* op = Oc + (size_t)(t0 + ty * 4 + i) * HH + tx * 8;
        float4 o0 = {acc[i][0], acc[i][1], acc[i][2], acc[i][3]};
        float4 o1 = {acc[i][4], acc[i][5], acc[i][6], acc[i][7]};
        *(float4*)op       = o0;
        *(float4*)(op + 4) = o1;
    }
}

// ---------------------------------------------------------------------------
// Output: out[bt][d] = sum_h O[bt][h] * Wo[d][h] + bo[d]
// ---------------------------------------------------------------------------
__global__ __launch_bounds__(256) void out_kernel(
    const float* __restrict__ O, const float* __restrict__ Wo,
    const float* __restrict__ bo, float* __restrict__ out)
{
    const int row0 = blockIdx.x * 64;
    const int d0   = blockIdx.y * 128;

    __shared__ float oT[32][68];
    __shared__ float woT[32][132];

    const int tid = threadIdx.x;
    const int tx = tid & 15;
    const int ty = tid >> 4;

    float acc[4][8];
    #pragma unroll
    for (int i = 0; i < 4; i++)
        #pragma unroll
        for (int j = 0; j < 8; j++) acc[i][j] = 0.f;

    for (int k0 = 0; k0 < HH; k0 += 32) {
        #pragma unroll
        for (int l = 0; l < 2; l++) {
            int f = tid + l * 256;
            int r = f >> 3;
            int cg = f & 7;
            float4 v = *(const float4*)(O + (size_t)(row0 + r) * HH + k0 + cg * 4);
            oT[cg*4+0][r] = v.x; oT[cg*4+1][r] = v.y;
            oT[cg*4+2][r] = v.z; oT[cg*4+3][r] = v.w;
        }
        #pragma unroll
        for (int l = 0; l < 4; l++) {
            int f = tid + l * 256;
            int d = f >> 3;
            int cg = f & 7;
            float4 v = *(const float4*)(Wo + (size_t)(d0 + d) * HH + k0 + cg * 4);
            woT[cg*4+0][d] = v.x; woT[cg*4+1][d] = v.y;
            woT[cg*4+2][d] = v.z; woT[cg*4+3][d] = v.w;
        }
        __syncthreads();
        #pragma unroll
        for (int kk = 0; kk < 32; kk++) {
            float4 ov = *(const float4*)&oT[kk][ty * 4];
            float4 w0 = *(const float4*)&woT[kk][tx * 8];
            float4 w1 = *(const float4*)&woT[kk][tx * 8 + 4];
            float oa[4] = {ov.x, ov.y, ov.z, ov.w};
            float wa[8] = {w0.x, w0.y, w0.z, w0.w, w1.x, w1.y, w1.z, w1.w};
            #pragma unroll
            for (int i = 0; i < 4; i++)
                #pragma unroll
                for (int j = 0; j < 8; j++)
                    acc[i][j] += oa[i] * wa[j];
        }
        __syncthreads();
    }

    #pragma unroll
    for (int i = 0; i < 4; i++) {
        int row = row0 + ty * 4 + i;
        #pragma unroll
        for (int j = 0; j < 8; j++) acc[i][j] += bo[d0 + tx * 8 + j];
        float4 o0 = {acc[i][0], acc[i][1], acc[i][2], acc[i][3]};
        float4 o1 = {acc[i][4], acc[i][5], acc[i][6], acc[i][7]};
        *(float4*)(out + (size_t)row * DD + d0 + tx * 8)     = o0;
        *(float4*)(out + (size_t)row * DD + d0 + tx * 8 + 4) = o1;
    }
}

extern "C" void kernel_launch(void* const* d_in, const int* in_sizes, int n_in,
                              void* d_out, int out_size, void* d_ws, size_t ws_size,
                              hipStream_t stream) {
    const float* x  = (const float*)d_in[0];
    const float* Wq = (const float*)d_in[1];
    const float* bq = (const float*)d_in[2];
    const float* Wk = (const float*)d_in[3];
    const float* bk = (const float*)d_in[4];
    const float* Wv = (const float*)d_in[5];
    const float* bv = (const float*)d_in[6];
    const float* Wo = (const float*)d_in[7];
    const float* bo = (const float*)d_in[8];
    float* out = (float*)d_out;

    float* ws = (float*)d_ws;
    float* Q = ws;
    float* K = ws + (size_t)BT * HH;
    float* V = ws + (size_t)2 * BT * HH;
    float* O = ws + (size_t)3 * BT * HH;

    // scratch in d_out (32 MB), all consumed before out_kernel:
    //   rns @ 0 (64 KB) | Alpha @ 1 MB (4 MB) | G @ 8 MB (4 MB) | Mpre @ 12 MB
    float*  db    = (float*)d_out;
    float2* rns   = (float2*)db;
    float*  Alpha = db + (1u << 18);
    float*  G     = db + (1u << 21);
    float*  Mpre  = db + 3u * (1u << 20);

    dim3 pgrid(BT / 64, 3);
    proj_kernel<<<pgrid, 256, 0, stream>>>(x, Wq, bq, Wk, bk, Wv, bv, Q, K, V);

    rns_kernel<<<BT / 4, 256, 0, stream>>>(K, Q, rns);

    scan_kernel<<<BB, 512, 0, stream>>>(K, rns, Alpha);

    dim3 ggrid(BB * NCH, 2);
    gram_kernel<<<ggrid, 256, 0, stream>>>(V, Alpha, G);

    dim3 fgrid(BB, HH * HH / 256);
    prefix_kernel<<<fgrid, 256, 0, stream>>>(G, Mpre);

    dim3 cgrid(BB * NCH, 2);
    ochunk_kernel<<<cgrid, 256, 0, stream>>>(Q, Alpha, V, Mpre, O);

    dim3 ogrid(BT / 64, DD / 128);
    out_kernel<<<ogrid, 256, 0, stream>>>(O, Wo, bo, out);
}